// Round 8
// baseline (687.696 us; speedup 1.0000x reference)
//
#include <hip/hip_runtime.h>

#define IN_F 4096
#define OUT_F 16384
#define MTOK 8192   // B*S

#define BM 128
#define BN 128
#define BKB 128                 // K-bytes (=elements, i8) per K-tile
#define NKT (IN_F / BKB)        // 32 K-tiles
#define NIT (NKT / 2)           // 16 iterations, 2 K-tiles each

typedef __attribute__((ext_vector_type(4)))  int   i32x4;
typedef __attribute__((ext_vector_type(4)))  float f32x4;

__device__ __forceinline__ void gload_lds16(const void* g, void* l) {
    __builtin_amdgcn_global_load_lds(
        (const __attribute__((address_space(1))) void*)g,
        (__attribute__((address_space(3))) void*)l,
        16, 0, 0);
}

// ---------------------------------------------------------------------------
// Kernel 1: per-token absmax -> int8 quantize x, store scale
// ---------------------------------------------------------------------------
__global__ __launch_bounds__(256) void k_quant(const float* __restrict__ x,
                                               char* __restrict__ xq,
                                               float* __restrict__ xs) {
    const int m = blockIdx.x;
    const int t = threadIdx.x;
    const float* xrow = x + (size_t)m * IN_F;

    f32x4 v[4];
    float mx = 0.f;
#pragma unroll
    for (int i = 0; i < 4; ++i) {
        v[i] = *(const f32x4*)&xrow[(i * 256 + t) * 4];
        mx = fmaxf(mx, fmaxf(fmaxf(fabsf(v[i].x), fabsf(v[i].y)),
                             fmaxf(fabsf(v[i].z), fabsf(v[i].w))));
    }
#pragma unroll
    for (int off = 32; off > 0; off >>= 1)
        mx = fmaxf(mx, __shfl_xor(mx, off));

    __shared__ float wmax[4];
    const int wid = t >> 6;
    if ((t & 63) == 0) wmax[wid] = mx;
    __syncthreads();
    const float scale = fmaxf(fmaxf(fmaxf(wmax[0], wmax[1]),
                                    fmaxf(wmax[2], wmax[3])), 1e-5f);
    const float inv = 127.0f / scale;

    int* xqi = (int*)(xq + (size_t)m * IN_F);
#pragma unroll
    for (int i = 0; i < 4; ++i) {
        int q0 = (int)rintf(fminf(fmaxf(v[i].x * inv, -128.f), 127.f));
        int q1 = (int)rintf(fminf(fmaxf(v[i].y * inv, -128.f), 127.f));
        int q2 = (int)rintf(fminf(fmaxf(v[i].z * inv, -128.f), 127.f));
        int q3 = (int)rintf(fminf(fmaxf(v[i].w * inv, -128.f), 127.f));
        xqi[i * 256 + t] = (q0 & 255) | ((q1 & 255) << 8) |
                           ((q2 & 255) << 16) | (q3 << 24);
    }
    if (t == 0) xs[m] = scale;
}

// ---------------------------------------------------------------------------
// Kernel 2: ternary int32 weights -> int8 pack
// ---------------------------------------------------------------------------
__global__ __launch_bounds__(256) void k_wconv(const int* __restrict__ wt,
                                               int* __restrict__ w8) {
    const int total4 = OUT_F * IN_F / 4;
    int idx = blockIdx.x * 256 + threadIdx.x;
    const int stride = gridDim.x * 256;
    for (; idx < total4; idx += stride) {
        i32x4 w = *(const i32x4*)&wt[(size_t)idx * 4];
        w8[idx] = (w.x & 255) | ((w.y & 255) << 8) |
                  ((w.z & 255) << 16) | (w.w << 24);
    }
}

// ---------------------------------------------------------------------------
// Kernel 3: i8 GEMM — R4's 8-phase schedule at 128x128 / 4 waves / 64 KB LDS
// -> 2 independent blocks per CU. Cross-block desync overlaps the LDS-read
// phases of one block with the MFMA phases of the other (R6/R7 showed
// same-block lockstep serializes the two pipes; registers forbid in-wave
// read pipelining at 248/256 regs).
//
// LDS: A[2buf][2half][64rows][128B] (buf*16384 + half*8192), B at +32768.
// Swizzle (R4-proven): phys chunk = logical ^ (row&7); staging permutes the
// global SOURCE within each row's 128B only. Fragment read: row = lane&15,
// chunk = (kk*4 + (lane>>4)) ^ (lane&7)  -> 0 bank conflicts (measured R4).
// Schedule per iter (buf0 = tile 2t, buf1 = 2t+1), stages race-free:
//  ph1 rd aLo,bLo(buf0)  stage A1(2t+1)     MFMA(lo,lo)
//  ph2 rd bHi(buf0)      --                 MFMA(lo,hi)
//  ph3 rd aHi(buf0)      stage B0(2t+2)     MFMA(hi,hi)   [B reads done ph2]
//  ph4 --                stage B1,A0(2t+2)  MFMA(hi,lo)   [A reads done ph3]
//                        vmcnt(6) -> retires tile 2t+1 exactly (read ph5)
//  ph5-8 mirror on buf1; stages A1(2t+2), B0/B1/A0(2t+3); vmcnt(6)
//  last iter: vmcnt(0) (tail stages skipped, must drain fully).
// ---------------------------------------------------------------------------
__global__ __launch_bounds__(256, 2) void k_gemm(
    const char*  __restrict__ Aq,     // [MTOK][IN_F] int8
    const char*  __restrict__ Bq,     // [OUT_F][IN_F] int8
    const float* __restrict__ xs,     // [MTOK]
    const float* __restrict__ wsp,    // [1]
    float*       __restrict__ C) {    // [MTOK][OUT_F]
    __shared__ __align__(16) char lds[65536];   // A: 0..32K, B: 32K..64K

    const int t    = threadIdx.x;
    const int lane = t & 63;
    const int wid  = t >> 6;          // 0..3
    const int wr   = wid >> 1;        // 0..1 (M half, 64 rows)
    const int wc   = wid & 1;         // 0..1 (N half, 64 cols)

    // XCD band mapping: grid 8192 = 64(M) x 128(N); XCD (bid&7) owns a
    // contiguous 16-wide bn band; bm sweeps slowest. Bijective.
    const int bid = blockIdx.x;
    const int bn  = (bid & 7) * 16 + ((bid >> 3) & 15);
    const int bm  = bid >> 7;
    const int mBase = bm * BM;
    const int nBase = bn * BN;

    // --- staging source: per-instr chunk pc (= t, and 256+t); row = pc>>3,
    // src col-chunk = ((pc&7) ^ (row&7)) * 16.  (256+t) has same c0, row+32.
    const int r0 = t >> 3;                       // 0..31
    const int c0 = ((t ^ r0) & 7) << 4;

#define STAGE_A(h, b, kt) do {                                                 \
        const size_t _s = (size_t)(mBase + (h) * 64 + r0) * IN_F + c0          \
                        + (size_t)(kt) * BKB;                                  \
        char* _d = lds + (b) * 16384 + (h) * 8192 + wid * 1024;                \
        gload_lds16(Aq + _s, _d);                                              \
        gload_lds16(Aq + _s + (size_t)32 * IN_F, _d + 4096);                   \
    } while (0)
#define STAGE_B(h, b, kt) do {                                                 \
        const size_t _s = (size_t)(nBase + (h) * 64 + r0) * IN_F + c0          \
                        + (size_t)(kt) * BKB;                                  \
        char* _d = lds + 32768 + (b) * 16384 + (h) * 8192 + wid * 1024;        \
        gload_lds16(Bq + _s, _d);                                              \
        gload_lds16(Bq + _s + (size_t)32 * IN_F, _d + 4096);                   \
    } while (0)

    // --- fragment read offsets (R4 pattern): row = lane&15,
    // phys chunk = (kk*4 + (lane>>4)) ^ (lane&7)
    int fOff[2];
#pragma unroll
    for (int kk = 0; kk < 2; ++kk)
        fOff[kk] = (lane & 15) * 128 + (((kk * 4 + (lane >> 4)) ^ (lane & 7)) << 4);
    const char* ldsA = lds + wr * 8192;              // + buf*16384 + mi*2048
    const char* ldsB = lds + 32768 + wc * 8192;      // + buf*16384 + ni*2048

#define RD_A(dst, bOfs, miB)                                                   \
    _Pragma("unroll")                                                          \
    for (int mi = 0; mi < 2; ++mi)                                             \
        _Pragma("unroll")                                                      \
        for (int kk = 0; kk < 2; ++kk)                                         \
            dst[mi][kk] = *(const i32x4*)(ldsA + (bOfs) +                      \
                              ((miB) + mi) * 2048 + fOff[kk]);
#define RD_B(dst, bOfs, niB)                                                   \
    _Pragma("unroll")                                                          \
    for (int ni = 0; ni < 2; ++ni)                                             \
        _Pragma("unroll")                                                      \
        for (int kk = 0; kk < 2; ++kk)                                         \
            dst[ni][kk] = *(const i32x4*)(ldsB + (bOfs) +                      \
                              ((niB) + ni) * 2048 + fOff[kk]);
// R4's proven MFMA order: mi -> ni -> kk innermost
#define MFMA_Q(Af, MIB, Bf, NIB)                                               \
    __builtin_amdgcn_s_setprio(1);                                             \
    _Pragma("unroll")                                                          \
    for (int mi = 0; mi < 2; ++mi)                                             \
        _Pragma("unroll")                                                      \
        for (int ni = 0; ni < 2; ++ni)                                         \
            _Pragma("unroll")                                                  \
            for (int kk = 0; kk < 2; ++kk)                                     \
                acc[(MIB) + mi][(NIB) + ni] =                                  \
                    __builtin_amdgcn_mfma_i32_16x16x64_i8(                     \
                        Af[mi][kk], Bf[ni][kk], acc[(MIB) + mi][(NIB) + ni],   \
                        0, 0, 0);                                              \
    __builtin_amdgcn_s_setprio(0);
#define BAR()   __builtin_amdgcn_s_barrier()
#define LGKM0() asm volatile("s_waitcnt lgkmcnt(0)" ::: "memory")
#define VM6()   asm volatile("s_waitcnt vmcnt(6)" ::: "memory")
#define VM0()   asm volatile("s_waitcnt vmcnt(0)" ::: "memory")

    i32x4 acc[4][4];
#pragma unroll
    for (int i = 0; i < 4; ++i)
#pragma unroll
        for (int j = 0; j < 4; ++j)
            acc[i][j] = (i32x4){0, 0, 0, 0};

    i32x4 aLo[2][2], aHi[2][2], bLo[2][2], bHi[2][2];

    // ---- prologue: tile0 fully (8 loads) + tile1 {B0,B1,A0} (6 loads)
    STAGE_A(0, 0, 0); STAGE_A(1, 0, 0); STAGE_B(0, 0, 0); STAGE_B(1, 0, 0);
    STAGE_B(0, 1, 1); STAGE_B(1, 1, 1); STAGE_A(0, 1, 1);
    VM6();           // tile0's 8 retired; tile1's 6 in flight
    BAR();

    for (int it = 0; it < NIT; ++it) {
        const int kt1 = 2 * it + 1;
        const int kn0 = 2 * it + 2;
        const int kn1 = 2 * it + 3;
        const bool more = (it < NIT - 1);

        // ---- ph1
        RD_A(aLo, 0, 0); RD_B(bLo, 0, 0);
        STAGE_A(1, 1, kt1);
        BAR(); LGKM0();
        MFMA_Q(aLo, 0, bLo, 0);
        BAR();
        // ---- ph2
        RD_B(bHi, 0, 2);
        BAR(); LGKM0();
        MFMA_Q(aLo, 0, bHi, 2);
        BAR();
        // ---- ph3  (buf0 B-reads ended at ph2 -> B stage safe)
        RD_A(aHi, 0, 2);
        if (more) STAGE_B(0, 0, kn0);
        BAR(); LGKM0();
        MFMA_Q(aHi, 2, bHi, 2);
        BAR();
        // ---- ph4  (buf0 A-reads ended at ph3 -> A stage safe)
        if (more) { STAGE_B(1, 0, kn0); STAGE_A(0, 0, kn0); }
        BAR();
        MFMA_Q(aHi, 2, bLo, 0);
        if (more) { VM6(); } else { VM0(); }
        BAR();
        // ---- ph5
        RD_A(aLo, 16384, 0); RD_B(bLo, 16384, 0);
        if (more) STAGE_A(1, 0, kn0);
        BAR(); LGKM0();
        MFMA_Q(aLo, 0, bLo, 0);
        BAR();
        // ---- ph6
        RD_B(bHi, 16384, 2);
        BAR(); LGKM0();
        MFMA_Q(aLo, 0, bHi, 2);
        BAR();
        // ---- ph7
        RD_A(aHi, 16384, 2);
        if (more) STAGE_B(0, 1, kn1);
        BAR(); LGKM0();
        MFMA_Q(aHi, 2, bHi, 2);
        BAR();
        // ---- ph8
        if (more) { STAGE_B(1, 1, kn1); STAGE_A(0, 1, kn1); }
        BAR();
        MFMA_Q(aHi, 2, bLo, 0);
        if (more) { VM6(); } else { VM0(); }
        BAR();
    }

    // ---- epilogue: D row = (lane>>4)*4 + r, col = lane&15 (verified R1-R4)
    const float wsc = wsp[0] * (1.0f / 127.0f);
#pragma unroll
    for (int mi = 0; mi < 4; ++mi) {
        float rs[4];
#pragma unroll
        for (int r = 0; r < 4; ++r)
            rs[r] = xs[mBase + wr * 64 + mi * 16 + (lane >> 4) * 4 + r] * wsc;
#pragma unroll
        for (int ni = 0; ni < 4; ++ni) {
            const int col = nBase + wc * 64 + ni * 16 + (lane & 15);
#pragma unroll
            for (int r = 0; r < 4; ++r) {
                const int row = mBase + wr * 64 + mi * 16 + (lane >> 4) * 4 + r;
                C[(size_t)row * OUT_F + col] = (float)acc[mi][ni][r] * rs[r];
            }
        }
    }
}

// ---------------------------------------------------------------------------
extern "C" void kernel_launch(void* const* d_in, const int* in_sizes, int n_in,
                              void* d_out, int out_size, void* d_ws, size_t ws_size,
                              hipStream_t stream) {
    const float* x   = (const float*)d_in[0];
    const int*   wt  = (const int*)d_in[1];
    const float* wsp = (const float*)d_in[2];
    float* out = (float*)d_out;

    char*  w8 = (char*)d_ws;
    char*  xq = (char*)d_ws + (size_t)OUT_F * IN_F;
    float* xs = (float*)((char*)d_ws + (size_t)OUT_F * IN_F
                                     + (size_t)MTOK * IN_F);

    k_wconv<<<8192, 256, 0, stream>>>(wt, (int*)w8);
    k_quant<<<MTOK, 256, 0, stream>>>(x, xq, xs);

    const int grid = (MTOK / BM) * (OUT_F / BN);  // 64 * 128 = 8192
    k_gemm<<<grid, 256, 0, stream>>>(xq, w8, xs, wsp, out);
}

// Round 9
// 650.516 us; speedup vs baseline: 1.0572x; 1.0572x over previous
//
#include <hip/hip_runtime.h>

#define IN_F 4096
#define OUT_F 16384
#define MTOK 8192   // B*S

#define BM 256
#define BN 256
#define BK 64
#define NKT (IN_F / BK)   // 64 K-tiles

typedef __attribute__((ext_vector_type(4)))  int   i32x4;
typedef __attribute__((ext_vector_type(4)))  float f32x4;

__device__ __forceinline__ void gload_lds16(const void* g, void* l) {
    __builtin_amdgcn_global_load_lds(
        (const __attribute__((address_space(1))) void*)g,
        (__attribute__((address_space(3))) void*)l,
        16, 0, 0);
}

// ---------------------------------------------------------------------------
// Kernel 1: per-token absmax -> int8 quantize x, store scale
// ---------------------------------------------------------------------------
__global__ __launch_bounds__(256) void k_quant(const float* __restrict__ x,
                                               char* __restrict__ xq,
                                               float* __restrict__ xs) {
    const int m = blockIdx.x;
    const int t = threadIdx.x;
    const float* xrow = x + (size_t)m * IN_F;

    f32x4 v[4];
    float mx = 0.f;
#pragma unroll
    for (int i = 0; i < 4; ++i) {
        v[i] = *(const f32x4*)&xrow[(i * 256 + t) * 4];
        mx = fmaxf(mx, fmaxf(fmaxf(fabsf(v[i].x), fabsf(v[i].y)),
                             fmaxf(fabsf(v[i].z), fabsf(v[i].w))));
    }
#pragma unroll
    for (int off = 32; off > 0; off >>= 1)
        mx = fmaxf(mx, __shfl_xor(mx, off));

    __shared__ float wmax[4];
    const int wid = t >> 6;
    if ((t & 63) == 0) wmax[wid] = mx;
    __syncthreads();
    const float scale = fmaxf(fmaxf(fmaxf(wmax[0], wmax[1]),
                                    fmaxf(wmax[2], wmax[3])), 1e-5f);
    const float inv = 127.0f / scale;

    int* xqi = (int*)(xq + (size_t)m * IN_F);
#pragma unroll
    for (int i = 0; i < 4; ++i) {
        int q0 = (int)rintf(fminf(fmaxf(v[i].x * inv, -128.f), 127.f));
        int q1 = (int)rintf(fminf(fmaxf(v[i].y * inv, -128.f), 127.f));
        int q2 = (int)rintf(fminf(fmaxf(v[i].z * inv, -128.f), 127.f));
        int q3 = (int)rintf(fminf(fmaxf(v[i].w * inv, -128.f), 127.f));
        xqi[i * 256 + t] = (q0 & 255) | ((q1 & 255) << 8) |
                           ((q2 & 255) << 16) | (q3 << 24);
    }
    if (t == 0) xs[m] = scale;
}

// ---------------------------------------------------------------------------
// Kernel 2: ternary int32 weights -> int8 pack
// ---------------------------------------------------------------------------
__global__ __launch_bounds__(256) void k_wconv(const int* __restrict__ wt,
                                               int* __restrict__ w8) {
    const int total4 = OUT_F * IN_F / 4;
    int idx = blockIdx.x * 256 + threadIdx.x;
    const int stride = gridDim.x * 256;
    for (; idx < total4; idx += stride) {
        i32x4 w = *(const i32x4*)&wt[(size_t)idx * 4];
        w8[idx] = (w.x & 255) | ((w.y & 255) << 8) |
                  ((w.z & 255) << 16) | (w.w << 24);
    }
}

// ---------------------------------------------------------------------------
// Kernel 3: i8 GEMM — 256x256 tile, BK=64, 8 waves (2Mx4N, wave 128x64),
// THREE-buffer LDS rotation, ONE barrier per K-tile.
//
// Why: R4's 8-phase put BAR+lgkmcnt(0) between every read batch and MFMA
// cluster -> LDS pipe (~218 us floor) and MFMA pipe (~278 us floor) fully
// serialized (measured 503 = 278+218). Here all 12 ds_reads + the 4-load
// stage are issued BEFORE the 32-MFMA cluster; the compiler inserts
// fine-grained counted lgkmcnt (m97 evidence) so reads/stages fly under
// the MFMAs. Race-freedom from the 3-buffer rotation: body(kt) reads
// buf kt%3 and stages kt+2 into buf (kt+2)%3 == (kt-1)%3, whose reads all
// completed before body(kt-1)'s ending barrier (every read's consumer MFMA
// is in-body, so its lgkm wait precedes the barrier).
//
// LDS 96KB: A bufs at x*16384 (256 rows x 64B), B at 49152 + x*16384.
// Swizzle: phys chunk = logical ^ (row&3); staging permutes global SOURCE
// within each row's 64B only (thread t: row t>>2, chunk (t^(t>>2))&3).
// Fragment read: row = lane&15, chunk = (lane>>4) ^ (lane&3) -> per-16-lane
// group all 32 banks hit exactly 2x (free 2-way).
// vmcnt ledger: stage = 4 loads/K-tile; vmcnt(4) at end of body retires
// exactly stage(kt+1) (needed next body); last 2 bodies: vmcnt(0).
// ---------------------------------------------------------------------------
__global__ __launch_bounds__(512, 2) void k_gemm(
    const char*  __restrict__ Aq,     // [MTOK][IN_F] int8
    const char*  __restrict__ Bq,     // [OUT_F][IN_F] int8
    const float* __restrict__ xs,     // [MTOK]
    const float* __restrict__ wsp,    // [1]
    float*       __restrict__ C) {    // [MTOK][OUT_F]
    __shared__ __align__(16) char lds[98304];   // A: 0..48K, B: 48K..96K

    const int t    = threadIdx.x;
    const int lane = t & 63;
    const int wid  = t >> 6;
    const int wr   = wid >> 2;        // 0..1  (M half, 128 rows)
    const int wc   = wid & 3;         // 0..3  (N quarter, 64 cols)

    // XCD band mapping: grid 2048 = 32(M) x 64(N); XCD (bid&7) owns an
    // 8-wide bn band. Bijective.
    const int bid = blockIdx.x;
    const int bn  = (bid & 7) * 8 + ((bid >> 3) & 7);
    const int bm  = bid >> 6;
    const int mBase = bm * BM;
    const int nBase = bn * BN;

    // --- staging source: thread t -> row t>>2 (0..127), 16B chunk
    // (t&3)^((t>>2)&3) within the row's 64B. Second load: row +128.
    const int r0 = t >> 2;
    const int c0 = ((t ^ (t >> 2)) & 3) << 4;

#define STAGE(kt, bx) do {                                                     \
        const size_t ks = (size_t)(kt) * BK;                                   \
        gload_lds16(Aq + (size_t)(mBase + r0) * IN_F + ks + c0,                \
                    lds + (bx) * 16384 + wid * 1024);                          \
        gload_lds16(Aq + (size_t)(mBase + 128 + r0) * IN_F + ks + c0,          \
                    lds + (bx) * 16384 + 8192 + wid * 1024);                   \
        gload_lds16(Bq + (size_t)(nBase + r0) * IN_F + ks + c0,                \
                    lds + 49152 + (bx) * 16384 + wid * 1024);                  \
        gload_lds16(Bq + (size_t)(nBase + 128 + r0) * IN_F + ks + c0,          \
                    lds + 49152 + (bx) * 16384 + 8192 + wid * 1024);           \
    } while (0)

    // --- fragment read offset: row = lane&15 (x64B), phys chunk
    // = (lane>>4) ^ (lane&3)
    const int fOff = (lane & 15) * 64 + ((((lane >> 4) ^ lane) & 3) << 4);
    const char* ldsA = lds + wr * 8192;            // + x*16384 + mi*1024
    const char* ldsB = lds + 49152 + wc * 4096;    // + x*16384 + ni*1024

#define BAR()   __builtin_amdgcn_s_barrier()
#define VM4()   asm volatile("s_waitcnt vmcnt(4)" ::: "memory")
#define VM0()   asm volatile("s_waitcnt vmcnt(0)" ::: "memory")

    i32x4 acc[8][4];
#pragma unroll
    for (int i = 0; i < 8; ++i)
#pragma unroll
        for (int j = 0; j < 4; ++j)
            acc[i][j] = (i32x4){0, 0, 0, 0};

    // ---- prologue: stage K-tile 0 -> buf0, 1 -> buf1; retire tile 0 only
    STAGE(0, 0);
    STAGE(1, 1);
    VM4();
    BAR();

    int x = 0, x2 = 2;   // kt % 3, (kt+2) % 3
    for (int kt = 0; kt < NKT; ++kt) {
        const int xo = x * 16384;
        const bool more = (kt + 2 < NKT);

        // batch-issue all fragment reads of buf x (compiler inserts
        // counted lgkmcnt before each consuming MFMA)
        i32x4 b[4], a[8];
#pragma unroll
        for (int ni = 0; ni < 4; ++ni)
            b[ni] = *(const i32x4*)(ldsB + xo + ni * 1024 + fOff);
#pragma unroll
        for (int mi = 0; mi < 8; ++mi)
            a[mi] = *(const i32x4*)(ldsA + xo + mi * 1024 + fOff);

        // stage kt+2 into the buffer fully consumed last body
        if (more) STAGE(kt + 2, x2);

        __builtin_amdgcn_s_setprio(1);
#pragma unroll
        for (int mi = 0; mi < 8; ++mi)
#pragma unroll
            for (int ni = 0; ni < 4; ++ni)
                acc[mi][ni] = __builtin_amdgcn_mfma_i32_16x16x64_i8(
                    a[mi], b[ni], acc[mi][ni], 0, 0, 0);
        __builtin_amdgcn_s_setprio(0);

        // retire stage(kt+1) (next body's buffer); keep stage(kt+2) in flight
        if (more) { VM4(); } else { VM0(); }
        BAR();

        x  = (x  == 2) ? 0 : x  + 1;
        x2 = (x2 == 2) ? 0 : x2 + 1;
    }

    // ---- epilogue: D row = (lane>>4)*4 + r, col = lane&15 (verified R1-R7)
    const float wsc = wsp[0] * (1.0f / 127.0f);
#pragma unroll
    for (int mi = 0; mi < 8; ++mi) {
        float rs[4];
#pragma unroll
        for (int r = 0; r < 4; ++r)
            rs[r] = xs[mBase + wr * 128 + mi * 16 + (lane >> 4) * 4 + r] * wsc;
#pragma unroll
        for (int ni = 0; ni < 4; ++ni) {
            const int col = nBase + wc * 64 + ni * 16 + (lane & 15);
#pragma unroll
            for (int r = 0; r < 4; ++r) {
                const int row = mBase + wr * 128 + mi * 16 + (lane >> 4) * 4 + r;
                C[(size_t)row * OUT_F + col] = (float)acc[mi][ni][r] * rs[r];
            }
        }
    }
}

// ---------------------------------------------------------------------------
extern "C" void kernel_launch(void* const* d_in, const int* in_sizes, int n_in,
                              void* d_out, int out_size, void* d_ws, size_t ws_size,
                              hipStream_t stream) {
    const float* x   = (const float*)d_in[0];
    const int*   wt  = (const int*)d_in[1];
    const float* wsp = (const float*)d_in[2];
    float* out = (float*)d_out;

    char*  w8 = (char*)d_ws;
    char*  xq = (char*)d_ws + (size_t)OUT_F * IN_F;
    float* xs = (float*)((char*)d_ws + (size_t)OUT_F * IN_F
                                     + (size_t)MTOK * IN_F);

    k_wconv<<<8192, 256, 0, stream>>>(wt, (int*)w8);
    k_quant<<<MTOK, 256, 0, stream>>>(x, xq, xs);

    const int grid = (MTOK / BM) * (OUT_F / BN);  // 32 * 64 = 2048
    k_gemm<<<grid, 512, 0, stream>>>(xq, w8, xs, wsp, out);
}

// Round 10
// 643.982 us; speedup vs baseline: 1.0679x; 1.0101x over previous
//
#include <hip/hip_runtime.h>

#define IN_F 4096
#define OUT_F 16384
#define MTOK 8192   // B*S

#define BM 256
#define BN 256
#define BK 64
#define NKT (IN_F / BK)   // 64 K-tiles

typedef __attribute__((ext_vector_type(4)))  int   i32x4;
typedef __attribute__((ext_vector_type(4)))  float f32x4;

__device__ __forceinline__ void gload_lds16(const void* g, void* l) {
    __builtin_amdgcn_global_load_lds(
        (const __attribute__((address_space(1))) void*)g,
        (__attribute__((address_space(3))) void*)l,
        16, 0, 0);
}

// ---------------------------------------------------------------------------
// Kernel 1: per-token absmax -> int8 quantize x, store scale
// ---------------------------------------------------------------------------
__global__ __launch_bounds__(256) void k_quant(const float* __restrict__ x,
                                               char* __restrict__ xq,
                                               float* __restrict__ xs) {
    const int m = blockIdx.x;
    const int t = threadIdx.x;
    const float* xrow = x + (size_t)m * IN_F;

    f32x4 v[4];
    float mx = 0.f;
#pragma unroll
    for (int i = 0; i < 4; ++i) {
        v[i] = *(const f32x4*)&xrow[(i * 256 + t) * 4];
        mx = fmaxf(mx, fmaxf(fmaxf(fabsf(v[i].x), fabsf(v[i].y)),
                             fmaxf(fabsf(v[i].z), fabsf(v[i].w))));
    }
#pragma unroll
    for (int off = 32; off > 0; off >>= 1)
        mx = fmaxf(mx, __shfl_xor(mx, off));

    __shared__ float wmax[4];
    const int wid = t >> 6;
    if ((t & 63) == 0) wmax[wid] = mx;
    __syncthreads();
    const float scale = fmaxf(fmaxf(fmaxf(wmax[0], wmax[1]),
                                    fmaxf(wmax[2], wmax[3])), 1e-5f);
    const float inv = 127.0f / scale;

    int* xqi = (int*)(xq + (size_t)m * IN_F);
#pragma unroll
    for (int i = 0; i < 4; ++i) {
        int q0 = (int)rintf(fminf(fmaxf(v[i].x * inv, -128.f), 127.f));
        int q1 = (int)rintf(fminf(fmaxf(v[i].y * inv, -128.f), 127.f));
        int q2 = (int)rintf(fminf(fmaxf(v[i].z * inv, -128.f), 127.f));
        int q3 = (int)rintf(fminf(fmaxf(v[i].w * inv, -128.f), 127.f));
        xqi[i * 256 + t] = (q0 & 255) | ((q1 & 255) << 8) |
                           ((q2 & 255) << 16) | (q3 << 24);
    }
    if (t == 0) xs[m] = scale;
}

// ---------------------------------------------------------------------------
// Kernel 2: ternary int32 weights -> int8 pack
// ---------------------------------------------------------------------------
__global__ __launch_bounds__(256) void k_wconv(const int* __restrict__ wt,
                                               int* __restrict__ w8) {
    const int total4 = OUT_F * IN_F / 4;
    int idx = blockIdx.x * 256 + threadIdx.x;
    const int stride = gridDim.x * 256;
    for (; idx < total4; idx += stride) {
        i32x4 w = *(const i32x4*)&wt[(size_t)idx * 4];
        w8[idx] = (w.x & 255) | ((w.y & 255) << 8) |
                  ((w.z & 255) << 16) | (w.w << 24);
    }
}

// ---------------------------------------------------------------------------
// Kernel 3: i8 GEMM — 256x256 tile, BK=64, 8 waves (2Mx4N, wave 128x64),
// THREE-buffer LDS rotation, ONE barrier per K-tile (R9 structure) with the
// CORRECT 64B-row swizzle (R2/R3's, which measured 0 conflicts):
//
//   phys chunk = logical ^ ((row>>1)&3)
//
// R9's (row&3) variant put fragment-read bank bases on a period-4 cycle
// {0,20,8,28} -> 4-way conflict (5.03e7 measured). With (row>>1)&3:
// r even -> bases {0,4,8,12}, r odd -> {16,20,24,28}, each hit exactly 2x
// per 16-lane group = free 2-way (per-lane verified, all 4 k-groups).
//
// Structure (R9): body(kt) batch-issues all 12 fragment ds_reads of buf
// kt%3, issues the 4-load stage of kt+2 into buf (kt+2)%3 (fully consumed
// in body(kt-1), barrier-passed -> race-free), then 32 MFMAs; compiler
// inserts counted lgkmcnt so reads+stages fly under the MFMA cluster.
// vmcnt(4) end-of-body retires exactly stage(kt+1); last 2 bodies vmcnt(0).
// ---------------------------------------------------------------------------
__global__ __launch_bounds__(512, 2) void k_gemm(
    const char*  __restrict__ Aq,     // [MTOK][IN_F] int8
    const char*  __restrict__ Bq,     // [OUT_F][IN_F] int8
    const float* __restrict__ xs,     // [MTOK]
    const float* __restrict__ wsp,    // [1]
    float*       __restrict__ C) {    // [MTOK][OUT_F]
    __shared__ __align__(16) char lds[98304];   // A: 0..48K, B: 48K..96K

    const int t    = threadIdx.x;
    const int lane = t & 63;
    const int wid  = t >> 6;
    const int wr   = wid >> 2;        // 0..1  (M half, 128 rows)
    const int wc   = wid & 3;         // 0..3  (N quarter, 64 cols)

    // XCD band mapping: grid 2048 = 32(M) x 64(N); XCD (bid&7) owns an
    // 8-wide bn band. Bijective.
    const int bid = blockIdx.x;
    const int bn  = (bid & 7) * 8 + ((bid >> 3) & 7);
    const int bm  = bid >> 6;
    const int mBase = bm * BM;
    const int nBase = bn * BN;

    // --- staging source: thread t -> row t>>2 (0..127), phys chunk t&3;
    // logical (source) chunk = (t&3) ^ ((row>>1)&3) = (t&3) ^ ((t>>3)&3).
    // Second load row+128: (row>>1)&3 unchanged (128 = 0 mod 8).
    const int r0 = t >> 2;
    const int c0 = (((t & 3) ^ ((t >> 3) & 3)) << 4);

#define STAGE(kt, bx) do {                                                     \
        const size_t ks = (size_t)(kt) * BK;                                   \
        gload_lds16(Aq + (size_t)(mBase + r0) * IN_F + ks + c0,                \
                    lds + (bx) * 16384 + wid * 1024);                          \
        gload_lds16(Aq + (size_t)(mBase + 128 + r0) * IN_F + ks + c0,          \
                    lds + (bx) * 16384 + 8192 + wid * 1024);                   \
        gload_lds16(Bq + (size_t)(nBase + r0) * IN_F + ks + c0,                \
                    lds + 49152 + (bx) * 16384 + wid * 1024);                  \
        gload_lds16(Bq + (size_t)(nBase + 128 + r0) * IN_F + ks + c0,          \
                    lds + 49152 + (bx) * 16384 + 8192 + wid * 1024);           \
    } while (0)

    // --- fragment read offset: row = lane&15 (x64B),
    // phys chunk = (lane>>4) ^ ((row>>1)&3);  ((lane>>1)&3 == (row>>1)&3)
    const int fOff = (lane & 15) * 64 + ((((lane >> 4) ^ (lane >> 1)) & 3) << 4);
    const char* ldsA = lds + wr * 8192;            // + x*16384 + mi*1024
    const char* ldsB = lds + 49152 + wc * 4096;    // + x*16384 + ni*1024

#define BAR()   __builtin_amdgcn_s_barrier()
#define VM4()   asm volatile("s_waitcnt vmcnt(4)" ::: "memory")
#define VM0()   asm volatile("s_waitcnt vmcnt(0)" ::: "memory")

    i32x4 acc[8][4];
#pragma unroll
    for (int i = 0; i < 8; ++i)
#pragma unroll
        for (int j = 0; j < 4; ++j)
            acc[i][j] = (i32x4){0, 0, 0, 0};

    // ---- prologue: stage K-tile 0 -> buf0, 1 -> buf1; retire tile 0 only
    STAGE(0, 0);
    STAGE(1, 1);
    VM4();
    BAR();

    int x = 0, x2 = 2;   // kt % 3, (kt+2) % 3
    for (int kt = 0; kt < NKT; ++kt) {
        const int xo = x * 16384;
        const bool more = (kt + 2 < NKT);

        // batch-issue all fragment reads of buf x (compiler inserts
        // counted lgkmcnt before each consuming MFMA)
        i32x4 b[4], a[8];
#pragma unroll
        for (int ni = 0; ni < 4; ++ni)
            b[ni] = *(const i32x4*)(ldsB + xo + ni * 1024 + fOff);
#pragma unroll
        for (int mi = 0; mi < 8; ++mi)
            a[mi] = *(const i32x4*)(ldsA + xo + mi * 1024 + fOff);

        // stage kt+2 into the buffer fully consumed last body
        if (more) STAGE(kt + 2, x2);

        __builtin_amdgcn_s_setprio(1);
#pragma unroll
        for (int mi = 0; mi < 8; ++mi)
#pragma unroll
            for (int ni = 0; ni < 4; ++ni)
                acc[mi][ni] = __builtin_amdgcn_mfma_i32_16x16x64_i8(
                    a[mi], b[ni], acc[mi][ni], 0, 0, 0);
        __builtin_amdgcn_s_setprio(0);

        // retire stage(kt+1) (next body's buffer); keep stage(kt+2) in flight
        if (more) { VM4(); } else { VM0(); }
        BAR();

        x  = (x  == 2) ? 0 : x  + 1;
        x2 = (x2 == 2) ? 0 : x2 + 1;
    }

    // ---- epilogue: D row = (lane>>4)*4 + r, col = lane&15 (verified R1-R9)
    const float wsc = wsp[0] * (1.0f / 127.0f);
#pragma unroll
    for (int mi = 0; mi < 8; ++mi) {
        float rs[4];
#pragma unroll
        for (int r = 0; r < 4; ++r)
            rs[r] = xs[mBase + wr * 128 + mi * 16 + (lane >> 4) * 4 + r] * wsc;
#pragma unroll
        for (int ni = 0; ni < 4; ++ni) {
            const int col = nBase + wc * 64 + ni * 16 + (lane & 15);
#pragma unroll
            for (int r = 0; r < 4; ++r) {
                const int row = mBase + wr * 128 + mi * 16 + (lane >> 4) * 4 + r;
                C[(size_t)row * OUT_F + col] = (float)acc[mi][ni][r] * rs[r];
            }
        }
    }
}

// ---------------------------------------------------------------------------
extern "C" void kernel_launch(void* const* d_in, const int* in_sizes, int n_in,
                              void* d_out, int out_size, void* d_ws, size_t ws_size,
                              hipStream_t stream) {
    const float* x   = (const float*)d_in[0];
    const int*   wt  = (const int*)d_in[1];
    const float* wsp = (const float*)d_in[2];
    float* out = (float*)d_out;

    char*  w8 = (char*)d_ws;
    char*  xq = (char*)d_ws + (size_t)OUT_F * IN_F;
    float* xs = (float*)((char*)d_ws + (size_t)OUT_F * IN_F
                                     + (size_t)MTOK * IN_F);

    k_wconv<<<8192, 256, 0, stream>>>(wt, (int*)w8);
    k_quant<<<MTOK, 256, 0, stream>>>(x, xq, xs);

    const int grid = (MTOK / BM) * (OUT_F / BN);  // 32 * 64 = 2048
    k_gemm<<<grid, 512, 0, stream>>>(xq, w8, xs, wsp, out);
}